// Round 1
// baseline (1262.082 us; speedup 1.0000x reference)
//
#include <hip/hip_runtime.h>

// GeoAggregator fused kernel, round 0 (fp32 compute, bf16 LDS staging).
// One block per batch row (1024 blocks x 256 threads), everything on-chip.
//
// LDS map (bytes):
//   A4   (Q/K/V bf16, [mat 3][head 8][g 2][key 128] x 16B) : 0      .. 98304
//   tokP (tokens bf16-packed [c2 64][s 128] u32)           : 98304  .. 131072
//   scb  (sincos [s 128][17] f32; 0..7 cos, 8..15 sin)     : 131072 .. 139776
//   pooled[128] f32                                        : 139776 .. 140288
//   dec1[64] f32                                           : 140288 .. 140544
//   dec2[32] f32                                           : 140544 .. 140672

#define SL 128
#define XD 8
#define DM 128

__device__ __forceinline__ unsigned bf16rne(float f) {
  unsigned u = __float_as_uint(f);
  return (u + 0x7fffu + ((u >> 16) & 1u)) >> 16;
}
__device__ __forceinline__ float bflo(unsigned u) { return __uint_as_float(u << 16); }
__device__ __forceinline__ float bfhi(unsigned u) { return __uint_as_float(u & 0xffff0000u); }

__global__ __launch_bounds__(256, 1) void geo_kernel(
    const float* __restrict__ x, const float* __restrict__ y, const float* __restrict__ coords,
    const float* __restrict__ W1x, const float* __restrict__ b1x,
    const float* __restrict__ W2x, const float* __restrict__ b2x,
    const float* __restrict__ W1y, const float* __restrict__ b1y,
    const float* __restrict__ W2y, const float* __restrict__ b2y,
    const float* __restrict__ ly,
    const float* __restrict__ Wq, const float* __restrict__ bq,
    const float* __restrict__ Wk, const float* __restrict__ bk,
    const float* __restrict__ Wv, const float* __restrict__ bv,
    const float* __restrict__ dW1, const float* __restrict__ db1,
    const float* __restrict__ dW2, const float* __restrict__ db2,
    const float* __restrict__ dW3, const float* __restrict__ db3,
    float* __restrict__ out)
{
  extern __shared__ char smem[];
  uint4*    A4     = (uint4*)smem;
  unsigned* tokP   = (unsigned*)(smem + 98304);
  float*    scb    = (float*)(smem + 131072);
  float*    pooled = (float*)(smem + 139776);
  float*    dec1   = (float*)(smem + 140288);
  float*    dec2   = (float*)(smem + 140544);

  const int b   = blockIdx.x;
  const int tid = threadIdx.x;

  // ---------------- Phase 1: tokenizer + sincos ----------------
  if (tid < 128) {
    const int s = tid;
    const float cx = coords[(b * SL + s) * 2 + 0];
    const float cy = coords[(b * SL + s) * 2 + 1];
    const float invf[4] = {1.0f, 0.1f, 0.01f, 0.001f};
#pragma unroll
    for (int p = 0; p < 4; ++p) {
      float ax = cx * invf[p], ay = cy * invf[p];
      scb[s * 17 + p]      = cosf(ax);
      scb[s * 17 + 4 + p]  = cosf(ay);
      scb[s * 17 + 8 + p]  = sinf(ax);
      scb[s * 17 + 12 + p] = sinf(ay);
    }
    float xv[8];
#pragma unroll
    for (int c = 0; c < 8; ++c) xv[c] = x[(b * SL + s) * XD + c];
    float h1[64];
#pragma unroll
    for (int j = 0; j < 64; ++j) {
      float pre = b1x[j];
#pragma unroll
      for (int c = 0; c < 8; ++c) pre += xv[c] * W1x[c * 64 + j];
      h1[j] = pre - tanhf(pre);
    }
    for (int a = 0; a < 32; ++a) {
      float e0 = b2x[2 * a], e1 = b2x[2 * a + 1];
#pragma unroll
      for (int c = 0; c < 64; ++c) {
        e0 += h1[c] * W2x[c * 64 + 2 * a];
        e1 += h1[c] * W2x[c * 64 + 2 * a + 1];
      }
      tokP[a * 128 + s] = bf16rne(e0) | (bf16rne(e1) << 16);
    }
  } else {
    const int s = tid - 128;
    if (s < SL - 1) {
      const float yv = y[b * (SL - 1) + s];
      float h1[64];
#pragma unroll
      for (int j = 0; j < 64; ++j) {
        float pre = b1y[j] + yv * W1y[j];
        h1[j] = pre - tanhf(pre);
      }
      for (int a = 0; a < 32; ++a) {
        float e0 = b2y[2 * a], e1 = b2y[2 * a + 1];
#pragma unroll
        for (int c = 0; c < 64; ++c) {
          e0 += h1[c] * W2y[c * 64 + 2 * a];
          e1 += h1[c] * W2y[c * 64 + 2 * a + 1];
        }
        tokP[(32 + a) * 128 + s] = bf16rne(e0) | (bf16rne(e1) << 16);
      }
    } else {
      for (int a = 0; a < 32; ++a)
        tokP[(32 + a) * 128 + 127] = bf16rne(ly[2 * a]) | (bf16rne(ly[2 * a + 1]) << 16);
    }
  }
  __syncthreads();

  // ---------------- Phase 2a: QKV projection + RoPE (all heads) ----------------
  {
    const bool isQ = (tid < 128);
    const int  s   = isQ ? tid : tid - 128;
    float cs[8], sn[8];
#pragma unroll
    for (int p = 0; p < 8; ++p) { cs[p] = scb[s * 17 + p]; sn[p] = scb[s * 17 + 8 + p]; }

    const float* __restrict__ WA = isQ ? Wq : Wv;
    const float* __restrict__ bA = isQ ? bq : bv;
    const int koff = isQ ? 0 : 64;

    float acc[192];
#pragma unroll
    for (int j = 0; j < 128; ++j) acc[j] = bA[j];
#pragma unroll
    for (int j = 0; j < 64; ++j) acc[128 + j] = bk[koff + j];

    for (int c2 = 0; c2 < 64; ++c2) {
      unsigned pk = tokP[c2 * 128 + s];
      float tv0 = bflo(pk), tv1 = bfhi(pk);
      const float* wa0 = WA + (2 * c2) * DM;
      const float* wa1 = wa0 + DM;
      const float* wk0 = Wk + (2 * c2) * DM + koff;
      const float* wk1 = wk0 + DM;
#pragma unroll
      for (int j = 0; j < 128; ++j) acc[j] += tv0 * wa0[j] + tv1 * wa1[j];
#pragma unroll
      for (int j = 0; j < 64; ++j) acc[128 + j] += tv0 * wk0[j] + tv1 * wk1[j];
    }

    if (isQ) {  // RoPE on q-row (all 8 heads, same per-token R)
#pragma unroll
      for (int h = 0; h < 8; ++h)
#pragma unroll
        for (int p = 0; p < 8; ++p) {
          float a0 = acc[h * 16 + 2 * p], a1 = acc[h * 16 + 2 * p + 1];
          acc[h * 16 + 2 * p]     = cs[p] * a0 - sn[p] * a1;
          acc[h * 16 + 2 * p + 1] = sn[p] * a0 + cs[p] * a1;
        }
    }
    // RoPE on the 4 k-heads this thread owns (v-row is never rotated)
#pragma unroll
    for (int hh = 0; hh < 4; ++hh)
#pragma unroll
      for (int p = 0; p < 8; ++p) {
        float a0 = acc[128 + hh * 16 + 2 * p], a1 = acc[128 + hh * 16 + 2 * p + 1];
        acc[128 + hh * 16 + 2 * p]     = cs[p] * a0 - sn[p] * a1;
        acc[128 + hh * 16 + 2 * p + 1] = sn[p] * a0 + cs[p] * a1;
      }

    const int m0 = isQ ? 0 : 2;
#pragma unroll
    for (int h = 0; h < 8; ++h)
#pragma unroll
      for (int g = 0; g < 2; ++g) {
        const int base = h * 16 + g * 8;
        uint4 u;
        u.x = bf16rne(acc[base + 0]) | (bf16rne(acc[base + 1]) << 16);
        u.y = bf16rne(acc[base + 2]) | (bf16rne(acc[base + 3]) << 16);
        u.z = bf16rne(acc[base + 4]) | (bf16rne(acc[base + 5]) << 16);
        u.w = bf16rne(acc[base + 6]) | (bf16rne(acc[base + 7]) << 16);
        A4[((m0 * 8 + h) * 2 + g) * 128 + s] = u;
      }
    const int hb = koff >> 4;  // 0 or 4
#pragma unroll
    for (int hh = 0; hh < 4; ++hh)
#pragma unroll
      for (int g = 0; g < 2; ++g) {
        const int base = 128 + hh * 16 + g * 8;
        uint4 u;
        u.x = bf16rne(acc[base + 0]) | (bf16rne(acc[base + 1]) << 16);
        u.y = bf16rne(acc[base + 2]) | (bf16rne(acc[base + 3]) << 16);
        u.z = bf16rne(acc[base + 4]) | (bf16rne(acc[base + 5]) << 16);
        u.w = bf16rne(acc[base + 6]) | (bf16rne(acc[base + 7]) << 16);
        A4[((8 + hb + hh) * 2 + g) * 128 + s] = u;
      }
  }
  __syncthreads();

  // ---------------- Phase 2b: flash attention (head = tid>>5, 4 queries/thread) --
  {
    const int h  = tid >> 5;
    const int qg = tid & 31;
    const uint4* __restrict__ Qb = A4 + ((0 * 8 + h) * 2) * 128;
    const uint4* __restrict__ Kb = A4 + ((1 * 8 + h) * 2) * 128;
    const uint4* __restrict__ Vb = A4 + ((2 * 8 + h) * 2) * 128;

    float q[4][16];
#pragma unroll
    for (int qq = 0; qq < 4; ++qq)
#pragma unroll
      for (int g = 0; g < 2; ++g) {
        uint4 u = Qb[g * 128 + qg * 4 + qq];
        q[qq][g * 8 + 0] = bflo(u.x) * 0.25f; q[qq][g * 8 + 1] = bfhi(u.x) * 0.25f;
        q[qq][g * 8 + 2] = bflo(u.y) * 0.25f; q[qq][g * 8 + 3] = bfhi(u.y) * 0.25f;
        q[qq][g * 8 + 4] = bflo(u.z) * 0.25f; q[qq][g * 8 + 5] = bfhi(u.z) * 0.25f;
        q[qq][g * 8 + 6] = bflo(u.w) * 0.25f; q[qq][g * 8 + 7] = bfhi(u.w) * 0.25f;
      }

    float o[4][16];
    float m[4], l[4];
#pragma unroll
    for (int qq = 0; qq < 4; ++qq) {
      m[qq] = -3.0e38f; l[qq] = 0.0f;
#pragma unroll
      for (int j = 0; j < 16; ++j) o[qq][j] = 0.0f;
    }

    for (int ck = 0; ck < 16; ++ck) {  // 16 chunks x 8 keys
      float s8[4][8];
#pragma unroll
      for (int kk = 0; kk < 8; ++kk) {
        const int key = ck * 8 + kk;
        uint4 u0 = Kb[key], u1 = Kb[128 + key];
        float kv[16];
        kv[0] = bflo(u0.x); kv[1] = bfhi(u0.x); kv[2]  = bflo(u0.y); kv[3]  = bfhi(u0.y);
        kv[4] = bflo(u0.z); kv[5] = bfhi(u0.z); kv[6]  = bflo(u0.w); kv[7]  = bfhi(u0.w);
        kv[8] = bflo(u1.x); kv[9] = bfhi(u1.x); kv[10] = bflo(u1.y); kv[11] = bfhi(u1.y);
        kv[12] = bflo(u1.z); kv[13] = bfhi(u1.z); kv[14] = bflo(u1.w); kv[15] = bfhi(u1.w);
#pragma unroll
        for (int qq = 0; qq < 4; ++qq) {
          float d = 0.0f;
#pragma unroll
          for (int j = 0; j < 16; ++j) d += q[qq][j] * kv[j];
          s8[qq][kk] = d;
        }
      }
#pragma unroll
      for (int qq = 0; qq < 4; ++qq) {
        float M = s8[qq][0];
#pragma unroll
        for (int kk = 1; kk < 8; ++kk) M = fmaxf(M, s8[qq][kk]);
        float Mn = fmaxf(m[qq], M);
        float al = __expf(m[qq] - Mn);
        m[qq] = Mn;
        l[qq] *= al;
#pragma unroll
        for (int j = 0; j < 16; ++j) o[qq][j] *= al;
      }
#pragma unroll
      for (int kk = 0; kk < 8; ++kk) {
        const int key = ck * 8 + kk;
        uint4 u0 = Vb[key], u1 = Vb[128 + key];
        float vv[16];
        vv[0] = bflo(u0.x); vv[1] = bfhi(u0.x); vv[2]  = bflo(u0.y); vv[3]  = bfhi(u0.y);
        vv[4] = bflo(u0.z); vv[5] = bfhi(u0.z); vv[6]  = bflo(u0.w); vv[7]  = bfhi(u0.w);
        vv[8] = bflo(u1.x); vv[9] = bfhi(u1.x); vv[10] = bflo(u1.y); vv[11] = bfhi(u1.y);
        vv[12] = bflo(u1.z); vv[13] = bfhi(u1.z); vv[14] = bflo(u1.w); vv[15] = bfhi(u1.w);
        float p[4];
#pragma unroll
        for (int qq = 0; qq < 4; ++qq) {
          p[qq] = __expf(s8[qq][kk] - m[qq]);
          l[qq] += p[qq];
        }
#pragma unroll
        for (int qq = 0; qq < 4; ++qq)
#pragma unroll
          for (int j = 0; j < 16; ++j) o[qq][j] += p[qq] * vv[j];
      }
    }

    float po[16];
#pragma unroll
    for (int j = 0; j < 16; ++j) po[j] = 0.0f;
#pragma unroll
    for (int qq = 0; qq < 4; ++qq) {
      float il = 1.0f / l[qq];
#pragma unroll
      for (int j = 0; j < 16; ++j) po[j] += o[qq][j] * il;
    }
    // reduce over the 32 lanes of this head's group (masks <=16 stay in-group)
    for (int r = 0; r < 5; ++r) {
      int mask = 1 << r;
#pragma unroll
      for (int j = 0; j < 16; ++j) po[j] += __shfl_xor(po[j], mask, 64);
    }
    if (qg == 0) {
#pragma unroll
      for (int j = 0; j < 16; ++j) pooled[h * 16 + j] = po[j] * (1.0f / 128.0f);
    }
  }
  __syncthreads();

  // ---------------- Phase 3: decoder ----------------
  if (tid < 64) {
    float a = db1[tid];
    for (int c = 0; c < 128; ++c) a += pooled[c] * dW1[c * 64 + tid];
    dec1[tid] = a - tanhf(a);
  }
  __syncthreads();
  if (tid < 32) {
    float a = db2[tid];
#pragma unroll
    for (int c = 0; c < 64; ++c) a += dec1[c] * dW2[c * 32 + tid];
    dec2[tid] = a - tanhf(a);
  }
  __syncthreads();
  if (tid == 0) {
    float a = db3[0];
#pragma unroll
    for (int c = 0; c < 32; ++c) a += dec2[c] * dW3[c];
    out[b] = a;
  }
}

extern "C" void kernel_launch(void* const* d_in, const int* in_sizes, int n_in,
                              void* d_out, int out_size, void* d_ws, size_t ws_size,
                              hipStream_t stream) {
  (void)in_sizes; (void)n_in; (void)d_ws; (void)ws_size; (void)out_size;
  const float* x      = (const float*)d_in[0];
  const float* y      = (const float*)d_in[1];
  const float* coords = (const float*)d_in[2];
  const float* W1x    = (const float*)d_in[3];
  const float* b1x    = (const float*)d_in[4];
  const float* W2x    = (const float*)d_in[5];
  const float* b2x    = (const float*)d_in[6];
  const float* W1y    = (const float*)d_in[7];
  const float* b1y    = (const float*)d_in[8];
  const float* W2y    = (const float*)d_in[9];
  const float* b2y    = (const float*)d_in[10];
  const float* ly     = (const float*)d_in[11];
  const float* Wq     = (const float*)d_in[12];
  const float* bq     = (const float*)d_in[13];
  const float* Wk     = (const float*)d_in[14];
  const float* bk     = (const float*)d_in[15];
  const float* Wv     = (const float*)d_in[16];
  const float* bv     = (const float*)d_in[17];
  const float* dW1    = (const float*)d_in[18];
  const float* db1    = (const float*)d_in[19];
  const float* dW2    = (const float*)d_in[20];
  const float* db2    = (const float*)d_in[21];
  const float* dW3    = (const float*)d_in[22];
  const float* db3    = (const float*)d_in[23];
  float* out = (float*)d_out;

  const int lds_bytes = 140672;
  hipFuncSetAttribute((const void*)geo_kernel,
                      hipFuncAttributeMaxDynamicSharedMemorySize, lds_bytes);
  geo_kernel<<<1024, 256, lds_bytes, stream>>>(
      x, y, coords, W1x, b1x, W2x, b2x, W1y, b1y, W2y, b2y, ly,
      Wq, bq, Wk, bk, Wv, bv, dW1, db1, dW2, db2, dW3, db3, out);
}

// Round 2
// 1160.455 us; speedup vs baseline: 1.0876x; 1.0876x over previous
//
#include <hip/hip_runtime.h>

// GeoAggregator fused kernel, round 1.
// 1024 blocks x 512 threads, 1 block/CU (140KB LDS), 8 waves/CU.
// Key change vs round 0: phase 2a split into 4 roles x 96 outputs/thread
// (compile-time indexed template) so accumulators stay in VGPRs (round 0's
// acc[192] > 168 VGPR forced scratch spills -> 1262us latency-bound).
//
// LDS map (bytes):
//   A4   (Q/K/V bf16, [mat 3][head 8][g 2][key 128] x 16B) : 0      .. 98304
//   tokP (tokens bf16-packed [c2 64][s 128] u32)           : 98304  .. 131072
//   scb  (sincos [s 128][17] f32; 0..7 cos, 8..15 sin)     : 131072 .. 139776
//   pooled[128] f32                                        : 139776 .. 140288
//   dec1[64] f32                                           : 140288 .. 140544
//   dec2[32] f32                                           : 140544 .. 140672

#define SL 128
#define XD 8
#define DM 128

__device__ __forceinline__ unsigned bf16rne(float f) {
  unsigned u = __float_as_uint(f);
  return (u + 0x7fffu + ((u >> 16) & 1u)) >> 16;
}
__device__ __forceinline__ float bflo(unsigned u) { return __uint_as_float(u << 16); }
__device__ __forceinline__ float bfhi(unsigned u) { return __uint_as_float(u & 0xffff0000u); }

// Phase 2a worker: computes 96 contiguous dims [GD0, GD0+96) of the
// concatenated [Q(0:128)|K(128:256)|V(256:384)] projection for token s,
// applies RoPE to the first NROT local heads, stores bf16 to A4.
template <int GD0, int NROT>
__device__ __forceinline__ void proj_role(
    const float* __restrict__ Wq, const float* __restrict__ Wk, const float* __restrict__ Wv,
    const float* __restrict__ bq, const float* __restrict__ bk, const float* __restrict__ bv,
    const unsigned* __restrict__ tokP, uint4* __restrict__ A4,
    const float* __restrict__ scb, int s)
{
  float acc[96];
#pragma unroll
  for (int j = 0; j < 96; ++j) {
    const int gd = GD0 + j;
    const int od = gd & 127;
    acc[j] = (gd < 128) ? bq[od] : (gd < 256) ? bk[od] : bv[od];
  }

  for (int c2 = 0; c2 < 64; ++c2) {
    unsigned pk = tokP[c2 * 128 + s];
    float tv0 = bflo(pk), tv1 = bfhi(pk);
#pragma unroll
    for (int j = 0; j < 96; ++j) {
      const int gd = GD0 + j;
      const int od = gd & 127;
      const float* __restrict__ W = (gd < 128) ? Wq : (gd < 256) ? Wk : Wv;
      acc[j] += tv0 * W[(2 * c2) * DM + od] + tv1 * W[(2 * c2 + 1) * DM + od];
    }
  }

  // RoPE on the first NROT local heads (Q and K heads; V heads never rotate)
  if (NROT > 0) {
    float cs[8], sn[8];
#pragma unroll
    for (int p = 0; p < 8; ++p) { cs[p] = scb[s * 17 + p]; sn[p] = scb[s * 17 + 8 + p]; }
#pragma unroll
    for (int lh = 0; lh < NROT; ++lh)
#pragma unroll
      for (int p = 0; p < 8; ++p) {
        float a0 = acc[lh * 16 + 2 * p], a1 = acc[lh * 16 + 2 * p + 1];
        acc[lh * 16 + 2 * p]     = cs[p] * a0 - sn[p] * a1;
        acc[lh * 16 + 2 * p + 1] = sn[p] * a0 + cs[p] * a1;
      }
  }

#pragma unroll
  for (int lh = 0; lh < 6; ++lh) {
    const int gd = GD0 + lh * 16;
    const int m  = gd >> 7;
    const int h  = (gd >> 4) & 7;
#pragma unroll
    for (int g = 0; g < 2; ++g) {
      const int base = lh * 16 + g * 8;
      uint4 u;
      u.x = bf16rne(acc[base + 0]) | (bf16rne(acc[base + 1]) << 16);
      u.y = bf16rne(acc[base + 2]) | (bf16rne(acc[base + 3]) << 16);
      u.z = bf16rne(acc[base + 4]) | (bf16rne(acc[base + 5]) << 16);
      u.w = bf16rne(acc[base + 6]) | (bf16rne(acc[base + 7]) << 16);
      A4[((m * 8 + h) * 2 + g) * 128 + s] = u;
    }
  }
}

__global__ __launch_bounds__(512, 1) void geo_kernel(
    const float* __restrict__ x, const float* __restrict__ y, const float* __restrict__ coords,
    const float* __restrict__ W1x, const float* __restrict__ b1x,
    const float* __restrict__ W2x, const float* __restrict__ b2x,
    const float* __restrict__ W1y, const float* __restrict__ b1y,
    const float* __restrict__ W2y, const float* __restrict__ b2y,
    const float* __restrict__ ly,
    const float* __restrict__ Wq, const float* __restrict__ bq,
    const float* __restrict__ Wk, const float* __restrict__ bk,
    const float* __restrict__ Wv, const float* __restrict__ bv,
    const float* __restrict__ dW1, const float* __restrict__ db1,
    const float* __restrict__ dW2, const float* __restrict__ db2,
    const float* __restrict__ dW3, const float* __restrict__ db3,
    float* __restrict__ out)
{
  extern __shared__ char smem[];
  uint4*    A4     = (uint4*)smem;
  unsigned* tokP   = (unsigned*)(smem + 98304);
  float*    scb    = (float*)(smem + 131072);
  float*    pooled = (float*)(smem + 139776);
  float*    dec1   = (float*)(smem + 140288);
  float*    dec2   = (float*)(smem + 140544);

  const int b   = blockIdx.x;
  const int tid = threadIdx.x;

  // ---------------- Phase 1: sincos + tokenizer ----------------
  {
    // sincos: 4 threads per token
    const int s = tid >> 2, p = tid & 3;
    const float cx = coords[(b * SL + s) * 2 + 0];
    const float cy = coords[(b * SL + s) * 2 + 1];
    const float invf = (p == 0) ? 1.0f : (p == 1) ? 0.1f : (p == 2) ? 0.01f : 0.001f;
    float ax = cx * invf, ay = cy * invf;
    scb[s * 17 + p]      = cosf(ax);
    scb[s * 17 + 4 + p]  = cosf(ay);
    scb[s * 17 + 8 + p]  = sinf(ax);
    scb[s * 17 + 12 + p] = sinf(ay);
  }
  if (tid < 256) {  // x-tokenizer: 2 threads per token, 32 output dims each
    const int s = tid >> 1, hh = tid & 1;
    float xv[8];
#pragma unroll
    for (int c = 0; c < 8; ++c) xv[c] = x[(b * SL + s) * XD + c];
    float h1[64];
#pragma unroll
    for (int j = 0; j < 64; ++j) {
      float pre = b1x[j];
#pragma unroll
      for (int c = 0; c < 8; ++c) pre += xv[c] * W1x[c * 64 + j];
      h1[j] = pre - tanhf(pre);
    }
#pragma unroll
    for (int k = 0; k < 16; ++k) {
      const int a = hh * 16 + k;
      float e0 = b2x[2 * a], e1 = b2x[2 * a + 1];
#pragma unroll
      for (int c = 0; c < 64; ++c) {
        e0 += h1[c] * W2x[c * 64 + 2 * a];
        e1 += h1[c] * W2x[c * 64 + 2 * a + 1];
      }
      tokP[a * 128 + s] = bf16rne(e0) | (bf16rne(e1) << 16);
    }
  } else {  // y-tokenizer
    const int t2 = tid - 256;
    const int s = t2 >> 1, hh = t2 & 1;
    if (s < SL - 1) {
      const float yv = y[b * (SL - 1) + s];
      float h1[64];
#pragma unroll
      for (int j = 0; j < 64; ++j) {
        float pre = b1y[j] + yv * W1y[j];
        h1[j] = pre - tanhf(pre);
      }
#pragma unroll
      for (int k = 0; k < 16; ++k) {
        const int a = hh * 16 + k;
        float e0 = b2y[2 * a], e1 = b2y[2 * a + 1];
#pragma unroll
        for (int c = 0; c < 64; ++c) {
          e0 += h1[c] * W2y[c * 64 + 2 * a];
          e1 += h1[c] * W2y[c * 64 + 2 * a + 1];
        }
        tokP[(32 + a) * 128 + s] = bf16rne(e0) | (bf16rne(e1) << 16);
      }
    } else {
#pragma unroll
      for (int k = 0; k < 16; ++k) {
        const int a = hh * 16 + k;
        tokP[(32 + a) * 128 + 127] = bf16rne(ly[2 * a]) | (bf16rne(ly[2 * a + 1]) << 16);
      }
    }
  }
  __syncthreads();

  // ---------------- Phase 2a: QKV projection + RoPE, 4 roles x 96 dims ----
  {
    const int role = tid >> 7;       // wave-uniform (waves 0-1,2-3,4-5,6-7)
    const int s    = tid & 127;
    if (role == 0)      proj_role<0,   6>(Wq, Wk, Wv, bq, bk, bv, tokP, A4, scb, s);
    else if (role == 1) proj_role<96,  6>(Wq, Wk, Wv, bq, bk, bv, tokP, A4, scb, s);
    else if (role == 2) proj_role<192, 4>(Wq, Wk, Wv, bq, bk, bv, tokP, A4, scb, s);
    else                proj_role<288, 0>(Wq, Wk, Wv, bq, bk, bv, tokP, A4, scb, s);
  }
  __syncthreads();

  // ---------------- Phase 2b: attention, 1 wave per head, 2 queries/thread --
  {
    const int h    = tid >> 6;       // == wave index
    const int lane = tid & 63;
    const uint4* __restrict__ Qb = A4 + ((0 * 8 + h) * 2) * 128;
    const uint4* __restrict__ Kb = A4 + ((1 * 8 + h) * 2) * 128;
    const uint4* __restrict__ Vb = A4 + ((2 * 8 + h) * 2) * 128;

    float q[2][16];
#pragma unroll
    for (int qq = 0; qq < 2; ++qq)
#pragma unroll
      for (int g = 0; g < 2; ++g) {
        uint4 u = Qb[g * 128 + lane * 2 + qq];
        q[qq][g * 8 + 0] = bflo(u.x) * 0.25f; q[qq][g * 8 + 1] = bfhi(u.x) * 0.25f;
        q[qq][g * 8 + 2] = bflo(u.y) * 0.25f; q[qq][g * 8 + 3] = bfhi(u.y) * 0.25f;
        q[qq][g * 8 + 4] = bflo(u.z) * 0.25f; q[qq][g * 8 + 5] = bfhi(u.z) * 0.25f;
        q[qq][g * 8 + 6] = bflo(u.w) * 0.25f; q[qq][g * 8 + 7] = bfhi(u.w) * 0.25f;
      }

    float o[2][16];
    float m[2], l[2];
#pragma unroll
    for (int qq = 0; qq < 2; ++qq) {
      m[qq] = -3.0e38f; l[qq] = 0.0f;
#pragma unroll
      for (int j = 0; j < 16; ++j) o[qq][j] = 0.0f;
    }

    for (int ck = 0; ck < 16; ++ck) {  // 16 chunks x 8 keys
      float s8[2][8];
#pragma unroll
      for (int kk = 0; kk < 8; ++kk) {
        const int key = ck * 8 + kk;
        uint4 u0 = Kb[key], u1 = Kb[128 + key];
        float kv[16];
        kv[0]  = bflo(u0.x); kv[1]  = bfhi(u0.x); kv[2]  = bflo(u0.y); kv[3]  = bfhi(u0.y);
        kv[4]  = bflo(u0.z); kv[5]  = bfhi(u0.z); kv[6]  = bflo(u0.w); kv[7]  = bfhi(u0.w);
        kv[8]  = bflo(u1.x); kv[9]  = bfhi(u1.x); kv[10] = bflo(u1.y); kv[11] = bfhi(u1.y);
        kv[12] = bflo(u1.z); kv[13] = bfhi(u1.z); kv[14] = bflo(u1.w); kv[15] = bfhi(u1.w);
#pragma unroll
        for (int qq = 0; qq < 2; ++qq) {
          float d = 0.0f;
#pragma unroll
          for (int j = 0; j < 16; ++j) d += q[qq][j] * kv[j];
          s8[qq][kk] = d;
        }
      }
#pragma unroll
      for (int qq = 0; qq < 2; ++qq) {
        float M = s8[qq][0];
#pragma unroll
        for (int kk = 1; kk < 8; ++kk) M = fmaxf(M, s8[qq][kk]);
        float Mn = fmaxf(m[qq], M);
        float al = __expf(m[qq] - Mn);
        m[qq] = Mn;
        l[qq] *= al;
#pragma unroll
        for (int j = 0; j < 16; ++j) o[qq][j] *= al;
      }
#pragma unroll
      for (int kk = 0; kk < 8; ++kk) {
        const int key = ck * 8 + kk;
        uint4 u0 = Vb[key], u1 = Vb[128 + key];
        float vv[16];
        vv[0]  = bflo(u0.x); vv[1]  = bfhi(u0.x); vv[2]  = bflo(u0.y); vv[3]  = bfhi(u0.y);
        vv[4]  = bflo(u0.z); vv[5]  = bfhi(u0.z); vv[6]  = bflo(u0.w); vv[7]  = bfhi(u0.w);
        vv[8]  = bflo(u1.x); vv[9]  = bfhi(u1.x); vv[10] = bflo(u1.y); vv[11] = bfhi(u1.y);
        vv[12] = bflo(u1.z); vv[13] = bfhi(u1.z); vv[14] = bflo(u1.w); vv[15] = bfhi(u1.w);
        float p[2];
#pragma unroll
        for (int qq = 0; qq < 2; ++qq) {
          p[qq] = __expf(s8[qq][kk] - m[qq]);
          l[qq] += p[qq];
        }
#pragma unroll
        for (int qq = 0; qq < 2; ++qq)
#pragma unroll
          for (int j = 0; j < 16; ++j) o[qq][j] += p[qq] * vv[j];
      }
    }

    float po[16];
#pragma unroll
    for (int j = 0; j < 16; ++j) po[j] = 0.0f;
#pragma unroll
    for (int qq = 0; qq < 2; ++qq) {
      float il = 1.0f / l[qq];
#pragma unroll
      for (int j = 0; j < 16; ++j) po[j] += o[qq][j] * il;
    }
    // full-wave reduction (64 lanes = this head's 128 queries)
#pragma unroll
    for (int r = 0; r < 6; ++r) {
      int mask = 1 << r;
#pragma unroll
      for (int j = 0; j < 16; ++j) po[j] += __shfl_xor(po[j], mask, 64);
    }
    if (lane == 0) {
#pragma unroll
      for (int j = 0; j < 16; ++j) pooled[h * 16 + j] = po[j] * (1.0f / 128.0f);
    }
  }
  __syncthreads();

  // ---------------- Phase 3: decoder ----------------
  if (tid < 64) {
    float a = db1[tid];
    for (int c = 0; c < 128; ++c) a += pooled[c] * dW1[c * 64 + tid];
    dec1[tid] = a - tanhf(a);
  }
  __syncthreads();
  if (tid < 32) {
    float a = db2[tid];
#pragma unroll
    for (int c = 0; c < 64; ++c) a += dec1[c] * dW2[c * 32 + tid];
    dec2[tid] = a - tanhf(a);
  }
  __syncthreads();
  if (tid == 0) {
    float a = db3[0];
#pragma unroll
    for (int c = 0; c < 32; ++c) a += dec2[c] * dW3[c];
    out[b] = a;
  }
}

extern "C" void kernel_launch(void* const* d_in, const int* in_sizes, int n_in,
                              void* d_out, int out_size, void* d_ws, size_t ws_size,
                              hipStream_t stream) {
  (void)in_sizes; (void)n_in; (void)d_ws; (void)ws_size; (void)out_size;
  const float* x      = (const float*)d_in[0];
  const float* y      = (const float*)d_in[1];
  const float* coords = (const float*)d_in[2];
  const float* W1x    = (const float*)d_in[3];
  const float* b1x    = (const float*)d_in[4];
  const float* W2x    = (const float*)d_in[5];
  const float* b2x    = (const float*)d_in[6];
  const float* W1y    = (const float*)d_in[7];
  const float* b1y    = (const float*)d_in[8];
  const float* W2y    = (const float*)d_in[9];
  const float* b2y    = (const float*)d_in[10];
  const float* ly     = (const float*)d_in[11];
  const float* Wq     = (const float*)d_in[12];
  const float* bq     = (const float*)d_in[13];
  const float* Wk     = (const float*)d_in[14];
  const float* bk     = (const float*)d_in[15];
  const float* Wv     = (const float*)d_in[16];
  const float* bv     = (const float*)d_in[17];
  const float* dW1    = (const float*)d_in[18];
  const float* db1    = (const float*)d_in[19];
  const float* dW2    = (const float*)d_in[20];
  const float* db2    = (const float*)d_in[21];
  const float* dW3    = (const float*)d_in[22];
  const float* db3    = (const float*)d_in[23];
  float* out = (float*)d_out;

  const int lds_bytes = 140672;
  hipFuncSetAttribute((const void*)geo_kernel,
                      hipFuncAttributeMaxDynamicSharedMemorySize, lds_bytes);
  geo_kernel<<<1024, 512, lds_bytes, stream>>>(
      x, y, coords, W1x, b1x, W2x, b2x, W1y, b1y, W2y, b2y, ly,
      Wq, bq, Wk, bk, Wv, bv, dW1, db1, dW2, db2, dW3, db3, out);
}